// Round 3
// baseline (1532.789 us; speedup 1.0000x reference)
//
#include <hip/hip_runtime.h>
#include <hip/hip_bf16.h>

// TGCN graph convolution: out = (L @ [inputs|hidden]) @ W + b
// N=16384, B=2, F=32, G=16, OUT=16.  Dominant cost: stream L (1.07 GB fp32).
// v4: NO LDS, NO barriers in the main GEMM.  v1-v3 (global_load_lds + barrier
// skeleton) were all within 1% of each other: LDS-DMA WAW hazards force the
// compiler's waitcnt pass to drain vmcnt every staging batch no matter how the
// sync is written.  Key structural fact: A (=L) has ZERO cross-wave reuse, so
// LDS staging of A is pure overhead; the MFMA A-fragment (lane: row=l&15,
// k=(l>>4)*8+{0..7}) loads directly from row-major L as 2 dwordx4/lane, and
// the B-fragment is one contiguous 16B read/lane from xt[c][n] (L2-resident,
// 768 KB/split per XCD).  Plain global->VGPR loads get per-register vmcnt
// tracking -> compiler pipelines them deeply.  A prefetched 1 tile ahead in
// registers; B same-iter from L2; 6 independent acc chains; SPLITK=4 ->
// 1024 blocks, no LDS, ~110 VGPR -> 16 waves/CU.
// Workspace: Xt bf16 3 MB @ ws+0, Cp fp32 partials 25.2 MB @ ws+4MB.

#define NN   16384
#define FF   32
#define GG   16
#define OUTD 16
#define C96  96
#define BM   64
#define BK   64
#define SPLITK 4
#define KCHUNK (NN / SPLITK)    // 4096
#define KITERS (KCHUNK / BK)    // 64
#define NWG   (NN / BM * SPLITK) // 1024

typedef __attribute__((ext_vector_type(8))) short short8;
typedef __attribute__((ext_vector_type(4))) float f32x4;

__device__ __forceinline__ unsigned short f2bf(float f) {
  __hip_bfloat16 h = __float2bfloat16(f);
  return __builtin_bit_cast(unsigned short, h);
}

// ---------------------------------------------------------------------------
// Prep: Xt[c][n] bf16, c = b*48 + (f | 32+g), via LDS transpose (coalesced).
// ---------------------------------------------------------------------------
__global__ __launch_bounds__(256) void prep_xt(const float* __restrict__ inp,
                                               const float* __restrict__ hid,
                                               unsigned short* __restrict__ xt) {
  __shared__ float lds_cat[C96][64];
  const int tid = threadIdx.x;
  const int n0 = blockIdx.x * 64;

#pragma unroll
  for (int r = 0; r < 2; ++r) {
    int fi = tid + r * 256;       // 0..511
    int n = fi >> 3;
    int f4 = fi & 7;
#pragma unroll
    for (int b = 0; b < 2; ++b) {
      const float4* src = (const float4*)(inp + ((size_t)b * NN + (n0 + n)) * FF) + f4;
      float4 v = *src;
      int c = b * 48 + f4 * 4;
      lds_cat[c + 0][n] = v.x;
      lds_cat[c + 1][n] = v.y;
      lds_cat[c + 2][n] = v.z;
      lds_cat[c + 3][n] = v.w;
    }
  }
  {
    int n = tid >> 2;
    int g4 = tid & 3;
#pragma unroll
    for (int b = 0; b < 2; ++b) {
      const float4* src = (const float4*)(hid + ((size_t)b * NN + (n0 + n)) * GG) + g4;
      float4 v = *src;
      int c = b * 48 + 32 + g4 * 4;
      lds_cat[c + 0][n] = v.x;
      lds_cat[c + 1][n] = v.y;
      lds_cat[c + 2][n] = v.z;
      lds_cat[c + 3][n] = v.w;
    }
  }
  __syncthreads();
#pragma unroll
  for (int r = 0; r < 3; ++r) {
    int u = tid + r * 256;
    int c = u >> 3;
    int nn = (u & 7) * 8;
    short8 o;
#pragma unroll
    for (int j = 0; j < 8; ++j) o[j] = (short)f2bf(lds_cat[c][nn + j]);
    *(short8*)(xt + (size_t)c * NN + n0 + nn) = o;
  }
}

// ---------------------------------------------------------------------------
// Main: Cp[split][m][c96] = partial L @ X over this block's K range.
// Direct-to-register MFMA GEMM, no LDS, no __syncthreads.
//   A-fragment: row = m0 + wave*16 + (lane&15), k = kk*32 + (lane>>4)*8 + j
//               -> 2 f32x4 loads per kk, cvt to bf16 in VALU.
//   B-fragment: col = t*16 + (lane&15), same k -> 1 short8 load per (kk,t)
//               from xt (L2-resident).
// ---------------------------------------------------------------------------
__global__ __launch_bounds__(256, 4) void spmm_main(const float* __restrict__ L,
                                                    const unsigned short* __restrict__ xt,
                                                    float* __restrict__ cp) {
  const int tid = threadIdx.x;
  const int wave = tid >> 6;
  const int lane = tid & 63;
  const int lq = lane >> 4;
  const int lr = lane & 15;

  // Bijective XCD remap: 1024 wgs; each XCD gets 128 consecutive swz values
  // -> one split-K B panel (768 KB) per XCD stays L2-resident.
  const int wg = blockIdx.x;
  const int swz = (wg & 7) * (NWG / 8) + (wg >> 3);   // [0,1024) bijective
  const int my = swz >> 8;                            // split-K index 0..3
  const int mx = swz & 255;                           // m-block 0..255
  const int m0 = mx * BM;
  const int kbase = my * KCHUNK;

  // lane-invariant bases (include lane's k-offset lq*8)
  const float* arow = L + (size_t)(m0 + wave * 16 + lr) * NN + kbase + lq * 8;
  const unsigned short* bb0 = xt + (size_t)(0 * 16 + lr) * NN + kbase + lq * 8;
  const unsigned short* bb1 = xt + (size_t)(1 * 16 + lr) * NN + kbase + lq * 8;
  const unsigned short* bb2 = xt + (size_t)(2 * 16 + lr) * NN + kbase + lq * 8;
  const unsigned short* bb3 = xt + (size_t)(3 * 16 + lr) * NN + kbase + lq * 8;
  const unsigned short* bb4 = xt + (size_t)(4 * 16 + lr) * NN + kbase + lq * 8;
  const unsigned short* bb5 = xt + (size_t)(5 * 16 + lr) * NN + kbase + lq * 8;
  const unsigned short* bb[6] = {bb0, bb1, bb2, bb3, bb4, bb5};

  f32x4 acc[6];
#pragma unroll
  for (int t = 0; t < 6; ++t) acc[t] = (f32x4){0.f, 0.f, 0.f, 0.f};

  // A prefetch registers (current tile / next tile)
  f32x4 aC[2][2], aN[2][2];
#pragma unroll
  for (int kk = 0; kk < 2; ++kk)
#pragma unroll
    for (int j = 0; j < 2; ++j)
      aC[kk][j] = *(const f32x4*)(arow + kk * 32 + j * 4);

  for (int it = 0; it < KITERS; ++it) {
    // prefetch A for tile it+1 (clamped re-read on the last iter; L2-hit)
    const int nx = (it + 1 < KITERS) ? (it + 1) : it;
#pragma unroll
    for (int kk = 0; kk < 2; ++kk)
#pragma unroll
      for (int j = 0; j < 2; ++j)
        aN[kk][j] = *(const f32x4*)(arow + nx * BK + kk * 32 + j * 4);

#pragma unroll
    for (int kk = 0; kk < 2; ++kk) {
      f32x4 a0 = aC[kk][0], a1 = aC[kk][1];
      short8 af;
      af[0] = (short)f2bf(a0[0]);
      af[1] = (short)f2bf(a0[1]);
      af[2] = (short)f2bf(a0[2]);
      af[3] = (short)f2bf(a0[3]);
      af[4] = (short)f2bf(a1[0]);
      af[5] = (short)f2bf(a1[1]);
      af[6] = (short)f2bf(a1[2]);
      af[7] = (short)f2bf(a1[3]);
#pragma unroll
      for (int t = 0; t < 6; ++t) {
        short8 bf = *(const short8*)(bb[t] + it * BK + kk * 32);
        acc[t] = __builtin_amdgcn_mfma_f32_16x16x32_bf16(af, bf, acc[t], 0, 0, 0);
      }
    }
#pragma unroll
    for (int kk = 0; kk < 2; ++kk)
#pragma unroll
      for (int j = 0; j < 2; ++j)
        aC[kk][j] = aN[kk][j];
  }

  // store split-K partial tile (each region written exactly once)
  float* cpd = cp + ((size_t)my * NN + m0) * C96;
#pragma unroll
  for (int t = 0; t < 6; ++t) {
    int col = t * 16 + lr;
#pragma unroll
    for (int r = 0; r < 4; ++r) {
      int row = wave * 16 + lq * 4 + r;
      cpd[(size_t)row * C96 + col] = acc[t][r];
    }
  }
}

// ---------------------------------------------------------------------------
// Epilogue: sum split-K partials, apply W[48x16] + bias, write out[2][N][16].
// ---------------------------------------------------------------------------
__global__ __launch_bounds__(256) void epilogue(const float* __restrict__ cp,
                                                const float* __restrict__ w,
                                                const float* __restrict__ bias,
                                                float* __restrict__ out) {
  __shared__ float lds_c[64 * 97];   // 64 nodes x 96 cols, +1 pad per row
  __shared__ float lds_w[48 * 16];
  __shared__ float lds_bias[16];
  const int tid = threadIdx.x;
  const int n0 = blockIdx.x * 64;

  for (int i = tid; i < 768; i += 256) lds_w[i] = w[i];
  if (tid < 16) lds_bias[tid] = bias[tid];

  const size_t base = (size_t)n0 * C96;
#pragma unroll
  for (int i = 0; i < 24; ++i) {
    int e = tid + i * 256;   // 0..6143 over [64 x 96]
    float s = 0.f;
#pragma unroll
    for (int sp = 0; sp < SPLITK; ++sp)
      s += cp[(size_t)sp * (NN * C96) + base + e];
    lds_c[e + e / 96] = s;   // node*97 + col
  }
  __syncthreads();

  const int node = tid >> 2;
  const int b = (tid >> 1) & 1;
  const int o0 = (tid & 1) * 8;
  const float* crow = &lds_c[node * 97 + b * 48];
  float accv[8];
#pragma unroll
  for (int o = 0; o < 8; ++o) accv[o] = lds_bias[o0 + o];
#pragma unroll
  for (int j = 0; j < 48; ++j) {
    float cv = crow[j];
#pragma unroll
    for (int o = 0; o < 8; ++o) accv[o] += cv * lds_w[j * 16 + o0 + o];
  }
  size_t ob = (size_t)b * (NN * OUTD) + (size_t)(n0 + node) * OUTD + o0;
  float4 v0 = {accv[0], accv[1], accv[2], accv[3]};
  float4 v1 = {accv[4], accv[5], accv[6], accv[7]};
  *(float4*)(out + ob) = v0;
  *(float4*)(out + ob + 4) = v1;
}

extern "C" void kernel_launch(void* const* d_in, const int* in_sizes, int n_in,
                              void* d_out, int out_size, void* d_ws, size_t ws_size,
                              hipStream_t stream) {
  (void)in_sizes; (void)n_in; (void)out_size; (void)ws_size;
  const float* inp = (const float*)d_in[0];   // [2,16384,32]
  const float* hid = (const float*)d_in[1];   // [2,16384*16]
  const float* lap = (const float*)d_in[2];   // [16384,16384]
  const float* wts = (const float*)d_in[3];   // [48,16]
  const float* bia = (const float*)d_in[4];   // [16]
  float* out = (float*)d_out;                 // [2,16384*16]

  unsigned short* xt = (unsigned short*)d_ws;                  // 3 MB bf16
  float* cp = (float*)((char*)d_ws + (4u << 20));              // 25.2 MB fp32

  prep_xt<<<NN / 64, 256, 0, stream>>>(inp, hid, xt);
  spmm_main<<<NWG, 256, 0, stream>>>(lap, xt, cp);
  epilogue<<<NN / 64, 256, 0, stream>>>(cp, wts, bia, out);
}

// Round 5
// 1386.812 us; speedup vs baseline: 1.1053x; 1.1053x over previous
//
#include <hip/hip_runtime.h>
#include <hip/hip_bf16.h>

// TGCN graph convolution: out = (L @ [inputs|hidden]) @ W + b
// N=16384, B=2, F=32, G=16, OUT=16.  Dominant cost: stream L (1.07 GB fp32).
// v5 (resubmit after container flake): proven global_load_lds skeleton;
// lever is inter-block de-phasing (TLP), not intra-block pipelining (v1-v3
// tied => scheduling-insensitive; the per-tile vmcnt(0) drain is covered by
// OTHER blocks' traffic).  SPLITK=8 -> 2048 wgs = 2 staggered scheduling
// rounds over 4 resident blocks/CU: completions continuously re-seed blocks
// at random phases -> flat HBM demand.  XCD swizzle gives each XCD exactly
// one split-K slice -> its 384 KB B-panel stays L2-resident.
// Workspace (ws = 4 GiB per the poison fill): Xt bf16 3 MB @ ws+0,
// Cp fp32 partials 50.3 MB @ ws+4MB.

#define NN   16384
#define FF   32
#define GG   16
#define OUTD 16
#define C96  96
#define BM   64
#define BK   64
#define SPLITK 8
#define KCHUNK (NN / SPLITK)     // 2048
#define KITERS (KCHUNK / BK)     // 32
#define NWG   (NN / BM * SPLITK) // 2048

typedef __attribute__((ext_vector_type(8))) short short8;
typedef __attribute__((ext_vector_type(4))) float f32x4;

using as1_void = __attribute__((address_space(1))) void;
using as3_void = __attribute__((address_space(3))) void;

__device__ __forceinline__ unsigned short f2bf(float f) {
  __hip_bfloat16 h = __float2bfloat16(f);
  return __builtin_bit_cast(unsigned short, h);
}

// ---------------------------------------------------------------------------
// Prep: Xt[c][n] bf16, c = b*48 + (f | 32+g), via LDS transpose (coalesced).
// ---------------------------------------------------------------------------
__global__ __launch_bounds__(256) void prep_xt(const float* __restrict__ inp,
                                               const float* __restrict__ hid,
                                               unsigned short* __restrict__ xt) {
  __shared__ float lds_cat[C96][64];
  const int tid = threadIdx.x;
  const int n0 = blockIdx.x * 64;

#pragma unroll
  for (int r = 0; r < 2; ++r) {
    int fi = tid + r * 256;       // 0..511
    int n = fi >> 3;
    int f4 = fi & 7;
#pragma unroll
    for (int b = 0; b < 2; ++b) {
      const float4* src = (const float4*)(inp + ((size_t)b * NN + (n0 + n)) * FF) + f4;
      float4 v = *src;
      int c = b * 48 + f4 * 4;
      lds_cat[c + 0][n] = v.x;
      lds_cat[c + 1][n] = v.y;
      lds_cat[c + 2][n] = v.z;
      lds_cat[c + 3][n] = v.w;
    }
  }
  {
    int n = tid >> 2;
    int g4 = tid & 3;
#pragma unroll
    for (int b = 0; b < 2; ++b) {
      const float4* src = (const float4*)(hid + ((size_t)b * NN + (n0 + n)) * GG) + g4;
      float4 v = *src;
      int c = b * 48 + 32 + g4 * 4;
      lds_cat[c + 0][n] = v.x;
      lds_cat[c + 1][n] = v.y;
      lds_cat[c + 2][n] = v.z;
      lds_cat[c + 3][n] = v.w;
    }
  }
  __syncthreads();
#pragma unroll
  for (int r = 0; r < 3; ++r) {
    int u = tid + r * 256;
    int c = u >> 3;
    int nn = (u & 7) * 8;
    short8 o;
#pragma unroll
    for (int j = 0; j < 8; ++j) o[j] = (short)f2bf(lds_cat[c][nn + j]);
    *(short8*)(xt + (size_t)c * NN + n0 + nn) = o;
  }
}

// ---------------------------------------------------------------------------
// Main: Cp[split][m][c96] = partial L @ X over this block's K range.
// A tile 64x64 fp32 (16 KB), B tile 96x64 bf16 (12 KB), single-buffered.
// XOR swizzle baked into the per-lane GLOBAL src of global_load_lds (LDS
// fills linearly at wave-uniform base + lane*16, lands swizzled):
//   A unit (row,cu4) at slot row*16 + (cu4 ^ (row&15));
//   B unit (c,kg8)  at slot c*8   + (kg8 ^ (c&7)).
// ---------------------------------------------------------------------------
__global__ __launch_bounds__(256, 4) void spmm_main(const float* __restrict__ L,
                                                    const unsigned short* __restrict__ xt,
                                                    float* __restrict__ cp) {
  __shared__ __align__(16) float lds_a[BM * BK];            // 16 KB
  __shared__ __align__(16) unsigned short lds_b[C96 * BK];  // 12 KB

  const int tid = threadIdx.x;
  const int wave = tid >> 6;
  const int lane = tid & 63;

  // Bijective XCD remap: 2048 wgs round-robin XCDs by (wg&7); each XCD gets
  // 256 consecutive swz values = exactly ONE split-K slice (my), so its
  // 384 KB B panel stays resident in that XCD's L2 across both rounds.
  const int wg = blockIdx.x;
  const int swz = (wg & 7) * (NWG / 8) + (wg >> 3);   // [0,2048) bijective
  const int my = swz >> 8;                            // split-K index 0..7
  const int mx = swz & 255;                           // m-block 0..255
  const int m0 = mx * BM;
  const int kbase = my * KCHUNK;

  // staging source/dest (k0-invariant parts)
  const float* asrc[4];
  float* adst[4];
#pragma unroll
  for (int a = 0; a < 4; ++a) {
    int s = wave * 256 + a * 64 + lane;
    int row = s >> 4;
    int cu = (s & 15) ^ (row & 15);
    asrc[a] = L + (size_t)(m0 + row) * NN + kbase + cu * 4;
    adst[a] = lds_a + (wave * 256 + a * 64) * 4;  // wave-uniform
  }
  const unsigned short* bsrc[3];
  unsigned short* bdst[3];
#pragma unroll
  for (int bi = 0; bi < 3; ++bi) {
    int s = wave * 192 + bi * 64 + lane;
    int c = s >> 3;
    int kg = (s & 7) ^ (c & 7);
    bsrc[bi] = xt + (size_t)c * NN + kbase + kg * 8;
    bdst[bi] = lds_b + (wave * 192 + bi * 64) * 8;  // wave-uniform
  }

  // fragment LDS offsets (iteration-invariant)
  const int rowA = wave * 16 + (lane & 15);
  const int lq = lane >> 4;
  int aoff[2][2];
#pragma unroll
  for (int kk = 0; kk < 2; ++kk) {
    int cu0 = kk * 8 + lq * 2;
    aoff[kk][0] = (rowA * 16 + (cu0 ^ (rowA & 15))) * 4;
    aoff[kk][1] = (rowA * 16 + ((cu0 + 1) ^ (rowA & 15))) * 4;
  }
  int boff[2][6];
#pragma unroll
  for (int kk = 0; kk < 2; ++kk)
#pragma unroll
    for (int t = 0; t < 6; ++t) {
      int c = t * 16 + (lane & 15);
      int kg = kk * 4 + lq;
      boff[kk][t] = (c * 8 + (kg ^ (c & 7))) * 8;
    }

  f32x4 acc[6];
#pragma unroll
  for (int t = 0; t < 6; ++t) acc[t] = (f32x4){0.f, 0.f, 0.f, 0.f};

  for (int it = 0; it < KITERS; ++it) {
    const int ko = it * BK;
#pragma unroll
    for (int a = 0; a < 4; ++a)
      __builtin_amdgcn_global_load_lds((const as1_void*)(asrc[a] + ko),
                                       (as3_void*)adst[a], 16, 0, 0);
#pragma unroll
    for (int bi = 0; bi < 3; ++bi)
      __builtin_amdgcn_global_load_lds((const as1_void*)(bsrc[bi] + ko),
                                       (as3_void*)bdst[bi], 16, 0, 0);
    __syncthreads();

#pragma unroll
    for (int kk = 0; kk < 2; ++kk) {
      f32x4 a0 = *(const f32x4*)(lds_a + aoff[kk][0]);
      f32x4 a1 = *(const f32x4*)(lds_a + aoff[kk][1]);
      short8 af;
      af[0] = (short)f2bf(a0[0]);
      af[1] = (short)f2bf(a0[1]);
      af[2] = (short)f2bf(a0[2]);
      af[3] = (short)f2bf(a0[3]);
      af[4] = (short)f2bf(a1[0]);
      af[5] = (short)f2bf(a1[1]);
      af[6] = (short)f2bf(a1[2]);
      af[7] = (short)f2bf(a1[3]);
#pragma unroll
      for (int t = 0; t < 6; ++t) {
        short8 bf = *(const short8*)(lds_b + boff[kk][t]);
        acc[t] = __builtin_amdgcn_mfma_f32_16x16x32_bf16(af, bf, acc[t], 0, 0, 0);
      }
    }
    __syncthreads();
  }

  // store split-K partial tile (each region written exactly once)
  float* cpd = cp + ((size_t)my * NN + m0) * C96;
#pragma unroll
  for (int t = 0; t < 6; ++t) {
    int col = t * 16 + (lane & 15);
#pragma unroll
    for (int r = 0; r < 4; ++r) {
      int row = wave * 16 + lq * 4 + r;
      cpd[(size_t)row * C96 + col] = acc[t][r];
    }
  }
}

// ---------------------------------------------------------------------------
// Epilogue: sum split-K partials, apply W[48x16] + bias, write out[2][N][16].
// ---------------------------------------------------------------------------
__global__ __launch_bounds__(256) void epilogue(const float* __restrict__ cp,
                                                const float* __restrict__ w,
                                                const float* __restrict__ bias,
                                                float* __restrict__ out) {
  __shared__ float lds_c[64 * 97];   // 64 nodes x 96 cols, +1 pad per row
  __shared__ float lds_w[48 * 16];
  __shared__ float lds_bias[16];
  const int tid = threadIdx.x;
  const int n0 = blockIdx.x * 64;

  for (int i = tid; i < 768; i += 256) lds_w[i] = w[i];
  if (tid < 16) lds_bias[tid] = bias[tid];

  const size_t base = (size_t)n0 * C96;
#pragma unroll
  for (int i = 0; i < 24; ++i) {
    int e = tid + i * 256;   // 0..6143 over [64 x 96]
    float s = 0.f;
#pragma unroll
    for (int sp = 0; sp < SPLITK; ++sp)
      s += cp[(size_t)sp * (NN * C96) + base + e];
    lds_c[e + e / 96] = s;   // node*97 + col
  }
  __syncthreads();

  const int node = tid >> 2;
  const int b = (tid >> 1) & 1;
  const int o0 = (tid & 1) * 8;
  const float* crow = &lds_c[node * 97 + b * 48];
  float accv[8];
#pragma unroll
  for (int o = 0; o < 8; ++o) accv[o] = lds_bias[o0 + o];
#pragma unroll
  for (int j = 0; j < 48; ++j) {
    float cv = crow[j];
#pragma unroll
    for (int o = 0; o < 8; ++o) accv[o] += cv * lds_w[j * 16 + o0 + o];
  }
  size_t ob = (size_t)b * (NN * OUTD) + (size_t)(n0 + node) * OUTD + o0;
  float4 v0 = {accv[0], accv[1], accv[2], accv[3]};
  float4 v1 = {accv[4], accv[5], accv[6], accv[7]};
  *(float4*)(out + ob) = v0;
  *(float4*)(out + ob + 4) = v1;
}

extern "C" void kernel_launch(void* const* d_in, const int* in_sizes, int n_in,
                              void* d_out, int out_size, void* d_ws, size_t ws_size,
                              hipStream_t stream) {
  (void)in_sizes; (void)n_in; (void)out_size; (void)ws_size;
  const float* inp = (const float*)d_in[0];   // [2,16384,32]
  const float* hid = (const float*)d_in[1];   // [2,16384*16]
  const float* lap = (const float*)d_in[2];   // [16384,16384]
  const float* wts = (const float*)d_in[3];   // [48,16]
  const float* bia = (const float*)d_in[4];   // [16]
  float* out = (float*)d_out;                 // [2,16384*16]

  unsigned short* xt = (unsigned short*)d_ws;                  // 3 MB bf16
  float* cp = (float*)((char*)d_ws + (4u << 20));              // 50.3 MB fp32

  prep_xt<<<NN / 64, 256, 0, stream>>>(inp, hid, xt);
  spmm_main<<<NWG, 256, 0, stream>>>(lap, xt, cp);
  epilogue<<<NN / 64, 256, 0, stream>>>(cp, wts, bia, out);
}

// Round 6
// 1364.511 us; speedup vs baseline: 1.1233x; 1.0163x over previous
//
#include <hip/hip_runtime.h>
#include <hip/hip_bf16.h>

// TGCN graph convolution: out = (L @ [inputs|hidden]) @ W + b
// N=16384, B=2, F=32, G=16, OUT=16.  Dominant cost: stream L (1.07 GB fp32).
// v6: split-K series was monotone (2:1329.5 < 4:1342.9 < 8:1386.8) -> fewer,
// longer row-streams win (DRAM page locality), and sync-structure is proven
// irrelevant (v1-v3 within 0.03%).  So: SPLITK=1 (each L row streamed once;
// no cp partials; epilogue fused into spmm tail -> one less kernel), BK=128
// (512-B contiguous chunk per row per tile, 2x v2), BM=32 -> 512 blocks =
// v2's proven-best 2 blocks/CU.  Wave (rhalf,chalf) owns rows rhalf*16+[0,16)
// x batch chalf -> W-apply is wave-private (no cross-wave reduce).
// Workspace: Xt bf16 3 MB @ ws+0 only.

#define NN   16384
#define FF   32
#define GG   16
#define OUTD 16
#define C96  96
#define BM   32
#define BK   128
#define KITERS (NN / BK)     // 128
#define NWG   (NN / BM)      // 512

typedef __attribute__((ext_vector_type(8))) short short8;
typedef __attribute__((ext_vector_type(4))) float f32x4;

using as1_void = __attribute__((address_space(1))) void;
using as3_void = __attribute__((address_space(3))) void;

__device__ __forceinline__ unsigned short f2bf(float f) {
  __hip_bfloat16 h = __float2bfloat16(f);
  return __builtin_bit_cast(unsigned short, h);
}

// ---------------------------------------------------------------------------
// Prep: Xt[c][n] bf16, c = b*48 + (f | 32+g), via LDS transpose (coalesced).
// ---------------------------------------------------------------------------
__global__ __launch_bounds__(256) void prep_xt(const float* __restrict__ inp,
                                               const float* __restrict__ hid,
                                               unsigned short* __restrict__ xt) {
  __shared__ float lds_cat[C96][64];
  const int tid = threadIdx.x;
  const int n0 = blockIdx.x * 64;

#pragma unroll
  for (int r = 0; r < 2; ++r) {
    int fi = tid + r * 256;       // 0..511
    int n = fi >> 3;
    int f4 = fi & 7;
#pragma unroll
    for (int b = 0; b < 2; ++b) {
      const float4* src = (const float4*)(inp + ((size_t)b * NN + (n0 + n)) * FF) + f4;
      float4 v = *src;
      int c = b * 48 + f4 * 4;
      lds_cat[c + 0][n] = v.x;
      lds_cat[c + 1][n] = v.y;
      lds_cat[c + 2][n] = v.z;
      lds_cat[c + 3][n] = v.w;
    }
  }
  {
    int n = tid >> 2;
    int g4 = tid & 3;
#pragma unroll
    for (int b = 0; b < 2; ++b) {
      const float4* src = (const float4*)(hid + ((size_t)b * NN + (n0 + n)) * GG) + g4;
      float4 v = *src;
      int c = b * 48 + 32 + g4 * 4;
      lds_cat[c + 0][n] = v.x;
      lds_cat[c + 1][n] = v.y;
      lds_cat[c + 2][n] = v.z;
      lds_cat[c + 3][n] = v.w;
    }
  }
  __syncthreads();
#pragma unroll
  for (int r = 0; r < 3; ++r) {
    int u = tid + r * 256;
    int c = u >> 3;
    int nn = (u & 7) * 8;
    short8 o;
#pragma unroll
    for (int j = 0; j < 8; ++j) o[j] = (short)f2bf(lds_cat[c][nn + j]);
    *(short8*)(xt + (size_t)c * NN + n0 + nn) = o;
  }
}

// ---------------------------------------------------------------------------
// Main (fused): out[b][n][o] for a 32-row band.  A tile 32x128 fp32 (16 KB),
// B tile 96x128 bf16 (24 KB), single-buffered (skeleton proven sync-
// insensitive).  XOR swizzle in the per-lane GLOBAL src of global_load_lds
// (LDS fills linearly, lands swizzled):
//   A 16B-unit (row,u) at slot row*32 + (u ^ (row&7));
//   B 16B-unit (c,  u) at slot c*16  + (u ^ (c&7)).
// Wave w = rhalf + 2*... : chalf = w&1 (batch), rhalf = w>>1 (row half).
// Each wave: 3 col-tiles x 16x16x32 MFMA over 4 k-slices per tile.
// Tail: ax -> LDS (wave-private), apply W[48x16]+bias, store out directly.
// ---------------------------------------------------------------------------
__global__ __launch_bounds__(256, 2) void spmm_fused(const float* __restrict__ L,
                                                     const unsigned short* __restrict__ xt,
                                                     const float* __restrict__ w,
                                                     const float* __restrict__ bias,
                                                     float* __restrict__ out) {
  __shared__ __align__(16) float lds_a[BM * BK];            // 16 KB
  __shared__ __align__(16) unsigned short lds_b[C96 * BK];  // 24 KB
  __shared__ float lds_w[48 * 16];
  __shared__ float lds_bias[16];

  const int tid = threadIdx.x;
  const int wave = tid >> 6;
  const int lane = tid & 63;
  const int lq = lane >> 4;
  const int lr = lane & 15;
  const int chalf = wave & 1;   // batch
  const int rhalf = wave >> 1;  // row half

  // W + bias into LDS once (first __syncthreads in the loop covers it)
  for (int i = tid; i < 768; i += 256) lds_w[i] = w[i];
  if (tid < 16) lds_bias[tid] = bias[tid];

  // Bijective XCD remap: 512 wgs; each XCD gets 64 consecutive m-blocks ->
  // a contiguous 2048-row band of L and the whole 3 MB xt panel in its L2.
  const int wg = blockIdx.x;
  const int mx = (wg & 7) * (NWG / 8) + (wg >> 3);    // [0,512) bijective
  const int m0 = mx * BM;

  // staging: A 1024 units (4/thread), B 1536 units (6/thread)
  const float* asrc[4];
  float* adst[4];
#pragma unroll
  for (int a = 0; a < 4; ++a) {
    int s = a * 256 + wave * 64 + lane;
    int row = s >> 5;              // 0..31
    int cu = (s & 31) ^ (row & 7); // swizzled global k-unit
    asrc[a] = L + (size_t)(m0 + row) * NN + cu * 4;
    adst[a] = lds_a + (a * 256 + wave * 64) * 4;   // wave-uniform
  }
  const unsigned short* bsrc[6];
  unsigned short* bdst[6];
#pragma unroll
  for (int bi = 0; bi < 6; ++bi) {
    int s = bi * 256 + wave * 64 + lane;
    int c = s >> 4;                // 0..95
    int kg = (s & 15) ^ (c & 7);   // swizzled global k-unit
    bsrc[bi] = xt + (size_t)c * NN + kg * 8;
    bdst[bi] = lds_b + (bi * 256 + wave * 64) * 8; // wave-uniform
  }

  // fragment LDS offsets (iteration-invariant, byte addresses in slots*16)
  const int rowA = rhalf * 16 + lr;
  int aoff[4][2];
#pragma unroll
  for (int kk = 0; kk < 4; ++kk)
#pragma unroll
    for (int j = 0; j < 2; ++j) {
      int ug = kk * 8 + lq * 2 + j;
      aoff[kk][j] = (rowA * 32 + (ug ^ (rowA & 7))) * 4;   // float index
    }
  int boff[4][3];
#pragma unroll
  for (int kk = 0; kk < 4; ++kk)
#pragma unroll
    for (int t = 0; t < 3; ++t) {
      int c = chalf * 48 + t * 16 + lr;
      int kg = kk * 4 + lq;
      boff[kk][t] = (c * 16 + (kg ^ (c & 7))) * 8;         // short index
    }

  f32x4 acc[3];
#pragma unroll
  for (int t = 0; t < 3; ++t) acc[t] = (f32x4){0.f, 0.f, 0.f, 0.f};

  for (int it = 0; it < KITERS; ++it) {
    const int ko = it * BK;
#pragma unroll
    for (int a = 0; a < 4; ++a)
      __builtin_amdgcn_global_load_lds((const as1_void*)(asrc[a] + ko),
                                       (as3_void*)adst[a], 16, 0, 0);
#pragma unroll
    for (int bi = 0; bi < 6; ++bi)
      __builtin_amdgcn_global_load_lds((const as1_void*)(bsrc[bi] + ko),
                                       (as3_void*)bdst[bi], 16, 0, 0);
    __syncthreads();

#pragma unroll
    for (int kk = 0; kk < 4; ++kk) {
      f32x4 a0 = *(const f32x4*)(lds_a + aoff[kk][0]);
      f32x4 a1 = *(const f32x4*)(lds_a + aoff[kk][1]);
      short8 af;
      af[0] = (short)f2bf(a0[0]);
      af[1] = (short)f2bf(a0[1]);
      af[2] = (short)f2bf(a0[2]);
      af[3] = (short)f2bf(a0[3]);
      af[4] = (short)f2bf(a1[0]);
      af[5] = (short)f2bf(a1[1]);
      af[6] = (short)f2bf(a1[2]);
      af[7] = (short)f2bf(a1[3]);
#pragma unroll
      for (int t = 0; t < 3; ++t) {
        short8 bf = *(const short8*)(lds_b + boff[kk][t]);
        acc[t] = __builtin_amdgcn_mfma_f32_16x16x32_bf16(af, bf, acc[t], 0, 0, 0);
      }
    }
    __syncthreads();
  }

  // ---- fused epilogue (wave-private; reuse lds_a as ax scratch) ----
  // wave region: 16 rows x 48 cols, stride 49 (pad)
  float* axl = lds_a + wave * (16 * 49);
#pragma unroll
  for (int t = 0; t < 3; ++t) {
    int col = t * 16 + lr;
#pragma unroll
    for (int r = 0; r < 4; ++r)
      axl[(lq * 4 + r) * 49 + col] = acc[t][r];
  }
  // no barrier needed: each wave reads only its own region (compiler inserts
  // the lgkm waits for the ds_write->ds_read dependency)
  const int node = lane >> 2;        // 0..15
  const int o0 = (lane & 3) * 4;     // 0,4,8,12
  float av[4];
#pragma unroll
  for (int o = 0; o < 4; ++o) av[o] = lds_bias[o0 + o];
#pragma unroll
  for (int j = 0; j < 48; ++j) {
    float cv = axl[node * 49 + j];
#pragma unroll
    for (int o = 0; o < 4; ++o) av[o] += cv * lds_w[j * 16 + o0 + o];
  }
  size_t ob = (size_t)chalf * (NN * OUTD) +
              (size_t)(m0 + rhalf * 16 + node) * OUTD + o0;
  float4 v = {av[0], av[1], av[2], av[3]};
  *(float4*)(out + ob) = v;
}

extern "C" void kernel_launch(void* const* d_in, const int* in_sizes, int n_in,
                              void* d_out, int out_size, void* d_ws, size_t ws_size,
                              hipStream_t stream) {
  (void)in_sizes; (void)n_in; (void)out_size; (void)ws_size;
  const float* inp = (const float*)d_in[0];   // [2,16384,32]
  const float* hid = (const float*)d_in[1];   // [2,16384*16]
  const float* lap = (const float*)d_in[2];   // [16384,16384]
  const float* wts = (const float*)d_in[3];   // [48,16]
  const float* bia = (const float*)d_in[4];   // [16]
  float* out = (float*)d_out;                 // [2,16384*16]

  unsigned short* xt = (unsigned short*)d_ws; // 3 MB bf16

  prep_xt<<<NN / 64, 256, 0, stream>>>(inp, hid, xt);
  spmm_fused<<<NWG, 256, 0, stream>>>(lap, xt, wts, bia, out);
}